// Round 8
// baseline (287.134 us; speedup 1.0000x reference)
//
#include <hip/hip_runtime.h>
#include <math.h>

#define B_ 4
#define L_ 2048
#define D_ 1024
#define H_ 16
#define DH_ 64
#define QKV_N 3072

typedef unsigned short ushort_t;
typedef unsigned int uint_t;
using bf16x8 = __attribute__((ext_vector_type(8))) short;
using f32x4  = __attribute__((ext_vector_type(4))) float;

__device__ __forceinline__ ushort_t f2bf(float f) {
    union { float f; unsigned int u; } v; v.f = f;
    unsigned int u = v.u;
    unsigned int rnd = ((u >> 16) & 1u) + 0x7fffu;
    return (ushort_t)((u + rnd) >> 16);
}

__device__ __forceinline__ float bf2f(ushort_t u) {
    union { unsigned int u; float f; } v;
    v.u = ((unsigned int)u) << 16;
    return v.f;
}

__device__ __forceinline__ void glds16(const void* g, void* l) {
    __builtin_amdgcn_global_load_lds(
        (const __attribute__((address_space(1))) unsigned int*)g,
        (__attribute__((address_space(3))) unsigned int*)l, 16, 0, 0);
}

// ---------------------------------------------------------------------------
// prep: blockIdx.z<4 -> transpose weight z into bf16 [n][k]; z==4 -> cast x.
// ---------------------------------------------------------------------------
__global__ __launch_bounds__(256) void prep(const float* __restrict__ Wq,
                                            const float* __restrict__ Wk,
                                            const float* __restrict__ Wv,
                                            const float* __restrict__ Wo,
                                            const float* __restrict__ x,
                                            ushort_t* __restrict__ wcat,
                                            ushort_t* __restrict__ wto,
                                            ushort_t* __restrict__ xb) {
    const int t = threadIdx.x;
    if (blockIdx.z == 4) {
        const int bid = blockIdx.y * 16 + blockIdx.x;
        const int base = bid * 32768 + t * 4;
        #pragma unroll
        for (int it = 0; it < 32; ++it) {
            float4 v = *(const float4*)(x + base + it * 1024);
            ushort4 o;
            o.x = f2bf(v.x); o.y = f2bf(v.y); o.z = f2bf(v.z); o.w = f2bf(v.w);
            *(ushort4*)(xb + base + it * 1024) = o;
        }
        return;
    }
    __shared__ ushort_t tile[64][65];
    const int widx = blockIdx.z;
    const float* W = (widx == 0) ? Wq : (widx == 1) ? Wk : (widx == 2) ? Wv : Wo;
    ushort_t* dst = (widx < 3) ? (wcat + (size_t)widx * 1024 * 1024) : wto;
    const int j = t & 63, i0 = t >> 6;
    const int kbase = blockIdx.y * 64, nbase = blockIdx.x * 64;
    #pragma unroll
    for (int it = 0; it < 16; ++it) {
        int i = it * 4 + i0;
        tile[i][j] = f2bf(W[(size_t)(kbase + i) * 1024 + nbase + j]);
    }
    __syncthreads();
    #pragma unroll
    for (int it = 0; it < 16; ++it) {
        int nn = it * 4 + i0;
        dst[(size_t)(nbase + nn) * 1024 + kbase + j] = tile[j][nn];
    }
}

// ---------------------------------------------------------------------------
// 256x128-tile 8-phase GEMM (T3+T4+T5), BK=64 in two 32-wide k-halves.
// QKV only: 768 blocks = 3.0 exact rounds at 1 block/CU (96 KiB LDS).
// Round-5 schedule == best measured (63.8 us, 807 TF, MfmaUtil 32.5%).
// Round-6's phase-merge (1 phase/K-tile, 3-buffer ring) REGRESSED to
// 75.1 us — confirms m196: coarse phase-split without the fine
// ds_read||stage||MFMA interleave hurts. Do not merge phases again.
// Waits: stage->consume distance is 3 phases; every full phase ends
// vmcnt(6) (9 loads = 3 regions outstanding -> region staged 2 phases
// ago landed one phase before consumption). Final iteration peeled:
// drain vm6 -> vm3 -> vm0 -> none.
// ---------------------------------------------------------------------------
__global__ __launch_bounds__(512) void gemm8p(const ushort_t* __restrict__ A,
                                              const ushort_t* __restrict__ Wt,
                                              ushort_t* __restrict__ Cbf,
                                              const ushort_t* __restrict__ resid,
                                              ushort_t* __restrict__ vt,
                                              int M, int N, int K, int fuse) {
    __shared__ ushort_t lds[49152];  // [buf]*24576 + [kh]*12288 + {A:0|B:8192}
    const int t = threadIdx.x;
    const int w = t >> 6, ln = t & 63;
    const int l15 = ln & 15, quad = ln >> 4;
    const int wrow = w >> 1, wcol = w & 1;

    // XCD-aware bijective block swizzle (grid has nwg % 8 == 0)
    int bx = blockIdx.x, by = blockIdx.y;
    {
        int nwg = gridDim.x * gridDim.y;
        if ((nwg & 7) == 0) {
            int flat = by * gridDim.x + bx;
            int nid = (flat & 7) * (nwg >> 3) + (flat >> 3);
            by = nid / gridDim.x;
            bx = nid - by * gridDim.x;
        }
    }
    const int bm = by * 256, bn = bx * 128;

    // staging source pointers (pre-swizzled global addresses)
    const ushort_t* Agp[2];
    const ushort_t* Bgp;
    #pragma unroll
    for (int j = 0; j < 2; ++j) {
        int r = j * 128 + (t >> 2);
        int c = (t & 3) ^ ((r >> 1) & 3);
        Agp[j] = A + (size_t)(bm + r) * K + c * 8;
    }
    {
        int r = t >> 2;
        int c = (t & 3) ^ ((r >> 1) & 3);
        Bgp = Wt + (size_t)(bn + r) * K + c * 8;
    }

    const int swz8 = (quad ^ ((l15 >> 1) & 3)) * 8;
    int aoff[4], boff[4];
    #pragma unroll
    for (int mf = 0; mf < 4; ++mf)
        aoff[mf] = (wrow * 64 + mf * 16 + l15) * 32 + swz8;
    #pragma unroll
    for (int nf = 0; nf < 4; ++nf)
        boff[nf] = (wcol * 64 + nf * 16 + l15) * 32 + swz8;

    f32x4 acc[4][4] = {};
    const int NT = K >> 6;

#define ABASE(BUF, KH) ((BUF) * 24576 + (KH) * 12288)
#define BBASE(BUF, KH) (ABASE(BUF, KH) + 8192)

#define STAGE(BUF, KH, KT) do {                                             \
        glds16(Agp[0] + (KT) * 64 + (KH) * 32, &lds[ABASE(BUF, KH) + t * 8]);\
        glds16(Agp[1] + (KT) * 64 + (KH) * 32,                              \
               &lds[ABASE(BUF, KH) + 4096 + t * 8]);                        \
        glds16(Bgp + (KT) * 64 + (KH) * 32, &lds[BBASE(BUF, KH) + t * 8]);  \
    } while (0)

#define VM6 asm volatile("s_waitcnt vmcnt(6)" ::: "memory")
#define VM3 asm volatile("s_waitcnt vmcnt(3)" ::: "memory")
#define VM0 asm volatile("s_waitcnt vmcnt(0)" ::: "memory")
#define NOVM ((void)0)

#define PHASE(BUF, KH, STAGEC, VMW) do {                                    \
        bf16x8 af_[4], bf_[4];                                              \
        _Pragma("unroll")                                                   \
        for (int m_ = 0; m_ < 4; ++m_)                                      \
            af_[m_] = *(const bf16x8*)&lds[ABASE(BUF, KH) + aoff[m_]];      \
        _Pragma("unroll")                                                   \
        for (int n_ = 0; n_ < 4; ++n_)                                      \
            bf_[n_] = *(const bf16x8*)&lds[BBASE(BUF, KH) + boff[n_]];      \
        STAGEC;                                                             \
        VMW;                                                                \
        __builtin_amdgcn_s_barrier();                                       \
        asm volatile("s_waitcnt lgkmcnt(0)" ::: "memory");                  \
        __builtin_amdgcn_s_setprio(1);                                      \
        _Pragma("unroll")                                                   \
        for (int m_ = 0; m_ < 4; ++m_)                                      \
            _Pragma("unroll")                                               \
            for (int n_ = 0; n_ < 4; ++n_)                                  \
                acc[m_][n_] = __builtin_amdgcn_mfma_f32_16x16x32_bf16(      \
                    af_[m_], bf_[n_], acc[m_][n_], 0, 0, 0);                \
        __builtin_amdgcn_s_setprio(0);                                      \
        __builtin_amdgcn_s_barrier();                                       \
    } while (0)

    // prologue: S1=b0k0(t0), S2=b0k1(t0), S3=b1k0(t1); 9 loads.
    STAGE(0, 0, 0);
    STAGE(0, 1, 0);
    STAGE(1, 0, 1);
    VM6;
    __builtin_amdgcn_s_barrier();

    // full iterations: every phase stages, every phase ends vmcnt(6)
    for (int it = 0; it < (NT >> 1) - 1; ++it) {
        const int kt1 = 2 * it + 1, kt2 = 2 * it + 2, kt3 = 2 * it + 3;
        PHASE(0, 0, STAGE(1, 1, kt1), VM6);
        PHASE(0, 1, STAGE(0, 0, kt2), VM6);
        PHASE(1, 0, STAGE(0, 1, kt2), VM6);
        PHASE(1, 1, STAGE(1, 0, kt3), VM6);
    }

    // peeled final iteration: drain 6 -> 3 -> 0.
    PHASE(0, 0, STAGE(1, 1, NT - 1), VM6);
    PHASE(0, 1, NOVM, VM3);
    PHASE(1, 0, NOVM, VM0);
    PHASE(1, 1, NOVM, NOVM);

#undef PHASE
#undef STAGE
#undef ABASE
#undef BBASE

    if (vt && bn >= 2048) {
        #pragma unroll
        for (int mf = 0; mf < 4; ++mf) {
            #pragma unroll
            for (int nf = 0; nf < 4; ++nf) {
                #pragma unroll
                for (int reg = 0; reg < 4; ++reg) {
                    int row = bm + wrow * 64 + mf * 16 + quad * 4 + reg;
                    int col = bn + wcol * 64 + nf * 16 + l15 - 2048;
                    int bb = row >> 11, tok = row & 2047;
                    int h = col >> 6, d = col & 63;
                    int tg = tok & 63;
                    int sc = (tg & 15) * 4 + (tg >> 4);
                    size_t addr = ((size_t)((bb * 16 + h) * 64 + d) << 11)
                                + (tok & ~63) + sc;
                    vt[addr] = f2bf(acc[mf][nf][reg]);
                }
            }
        }
    } else {
        #pragma unroll
        for (int mf = 0; mf < 4; ++mf) {
            #pragma unroll
            for (int nf = 0; nf < 4; ++nf) {
                #pragma unroll
                for (int reg = 0; reg < 4; ++reg) {
                    int row = bm + wrow * 64 + mf * 16 + quad * 4 + reg;
                    int col = bn + wcol * 64 + nf * 16 + l15;
                    size_t idx = (size_t)row * N + col;
                    float v = acc[mf][nf][reg];
                    if (fuse) v = fmaxf(v, 0.f) + bf2f(resid[idx]);
                    Cbf[idx] = f2bf(v);
                }
            }
        }
    }
}

// ---------------------------------------------------------------------------
// bf16 MFMA GEMM, tile 128x128, BK=64. Used for out-proj: 512 blocks at
// 3-4 blocks/CU — inter-block overlap hides prologue/epilogue (the 8-phase
// variant at 1.0 rounds lost 14 us to exposed tails, round-3 post-mortem).
// ---------------------------------------------------------------------------
__global__ __launch_bounds__(256) void gemm_mfma(const ushort_t* __restrict__ A,
                                                 const ushort_t* __restrict__ Wt,
                                                 ushort_t* __restrict__ Cbf,
                                                 const ushort_t* __restrict__ resid,
                                                 ushort_t* __restrict__ vt,
                                                 int M, int N, int K, int fuse) {
    __shared__ ushort_t As[128 * 64];
    __shared__ ushort_t Bs[128 * 64];
    const int t = threadIdx.x;
    const int w = t >> 6, ln = t & 63;
    const int l15 = ln & 15, quad = ln >> 4;
    const int bm = blockIdx.y * 128, bn = blockIdx.x * 128;
    const int wm = (w & 1) * 64, wn = (w >> 1) * 64;

    const ushort_t* Ap[4];
    const ushort_t* Bp[4];
    #pragma unroll
    for (int j = 0; j < 4; ++j) {
        const int i = t + j * 256;
        const int r = i >> 3;
        const int qg = (i & 7) ^ (r & 7);
        Ap[j] = A  + (size_t)(bm + r) * K + qg * 8;
        Bp[j] = Wt + (size_t)(bn + r) * K + qg * 8;
    }

    f32x4 acc[4][4] = {};

    for (int k0 = 0; k0 < K; k0 += 64) {
        __syncthreads();
        #pragma unroll
        for (int j = 0; j < 4; ++j) {
            glds16(Ap[j] + k0, &As[(t + j * 256) * 8]);
            glds16(Bp[j] + k0, &Bs[(t + j * 256) * 8]);
        }
        __syncthreads();

        #pragma unroll
        for (int kw = 0; kw < 2; ++kw) {
            bf16x8 af[4], bfr[4];
            #pragma unroll
            for (int im = 0; im < 4; ++im) {
                int row = wm + im * 16 + l15;
                int phys = (kw * 4 + quad) ^ (row & 7);
                af[im] = *(const bf16x8*)&As[row * 64 + phys * 8];
            }
            #pragma unroll
            for (int in = 0; in < 4; ++in) {
                int row = wn + in * 16 + l15;
                int phys = (kw * 4 + quad) ^ (row & 7);
                bfr[in] = *(const bf16x8*)&Bs[row * 64 + phys * 8];
            }
            #pragma unroll
            for (int im = 0; im < 4; ++im)
                #pragma unroll
                for (int in = 0; in < 4; ++in)
                    acc[im][in] = __builtin_amdgcn_mfma_f32_16x16x32_bf16(
                        af[im], bfr[in], acc[im][in], 0, 0, 0);
        }
    }

    if (vt && bn >= 2048) {
        #pragma unroll
        for (int im = 0; im < 4; ++im) {
            #pragma unroll
            for (int in = 0; in < 4; ++in) {
                #pragma unroll
                for (int reg = 0; reg < 4; ++reg) {
                    int row = bm + wm + im * 16 + quad * 4 + reg;
                    int col = bn + wn + in * 16 + l15 - 2048;
                    int bb = row >> 11, tok = row & 2047;
                    int h = col >> 6, d = col & 63;
                    int tg = tok & 63;
                    int sc = (tg & 15) * 4 + (tg >> 4);
                    size_t addr = ((size_t)((bb * 16 + h) * 64 + d) << 11)
                                + (tok & ~63) + sc;
                    vt[addr] = f2bf(acc[im][in][reg]);
                }
            }
        }
    } else {
        #pragma unroll
        for (int im = 0; im < 4; ++im) {
            #pragma unroll
            for (int in = 0; in < 4; ++in) {
                #pragma unroll
                for (int reg = 0; reg < 4; ++reg) {
                    int row = bm + wm + im * 16 + quad * 4 + reg;
                    int col = bn + wn + in * 16 + l15;
                    size_t idx = (size_t)row * N + col;
                    float v = acc[im][in][reg];
                    if (fuse) v = fmaxf(v, 0.f) + bf2f(resid[idx]);
                    Cbf[idx] = f2bf(v);
                }
            }
        }
    }
}

// ---------------------------------------------------------------------------
// Flash attention, bf16 MFMA, static-max softmax. Block = 4 waves, 128
// queries (wave w: 32). Round-8: 64-key tiles, 2-buffer K/V ring,
// stage-ahead-1 — next tile's 4 glds are ISSUED before the current tile's
// compute, so HBM/L2 latency hides under QK+softmax+PV; the implicit
// vmcnt(0) in __syncthreads() then drains already-landed loads.
// Barriers per key unchanged (1 per 64-key tile == 2 per 128-key tile).
// Arithmetic order identical to the 128-key version (kk=2t == (kt=t,ph=0),
// kk=2t+1 == (kt,ph=1)) -> bit-identical output.
// Race audit: RAW (stage kk+1 -> read kk+1) closed by end-of-iter
// syncthreads (vmcnt(0)+barrier); WAR (read buf in iter kk-1 -> glds
// overwrite in iter kk) closed because ds_reads complete before their
// MFMAs (lgkm waits) which precede the barrier that precedes the issue.
// LDS 50 KB -> 3 blocks/CU preserved. Masked tiles: maskedTile = kk>=2Qt;
// kk==2Qt+1 fully masked for w<2 -> compute skipped, barriers kept.
// T5 setprio around MFMA clusters retained.
// ---------------------------------------------------------------------------
__global__ __launch_bounds__(256) void attn_mfma(const ushort_t* __restrict__ qkv,
                                                 const ushort_t* __restrict__ Vt,
                                                 ushort_t* __restrict__ Zb) {
    __shared__ ushort_t Ks[2][64 * 64];
    __shared__ ushort_t Vs[2][64 * 64];
    __shared__ ushort_t Ps[4][32 * 72];
    const int t = threadIdx.x, w = t >> 6, ln = t & 63;
    const int l15 = ln & 15, quad = ln >> 4;
    const int bh = blockIdx.x;
    const int b = bh >> 4, h = bh & 15;
    const int Qt = 15 - blockIdx.y;

    bf16x8 ones;
    #pragma unroll
    for (int i = 0; i < 8; ++i) ones[i] = (short)0x3f80;

    // staging indices: 2 rows per thread for each of K(64x64) and V(64x64);
    // chunk swizzle phys = logical ^ (row&7), inverse applied on global src.
    int sr[2], sc[2];
    #pragma unroll
    for (int j = 0; j < 2; ++j) {
        int i = t + j * 256;
        sr[j] = i >> 3;                  // row 0..63
        sc[j] = (i & 7) ^ (sr[j] & 7);   // pre-swizzled source chunk
    }
    const ushort_t* Kgb = qkv + 1024 + (size_t)b * L_ * QKV_N + h * DH_;
    const ushort_t* Vgb = Vt + (size_t)((b * H_ + h) * DH_) * L_;

    bf16x8 qf[2][2];
    #pragma unroll
    for (int mt = 0; mt < 2; ++mt) {
        const ushort_t* qrow =
            qkv + (size_t)(b * L_ + Qt * 128 + w * 32 + mt * 16 + l15) * QKV_N + h * DH_;
        qf[mt][0] = *(const bf16x8*)(qrow + quad * 8);
        qf[mt][1] = *(const bf16x8*)(qrow + 32 + quad * 8);
    }

    f32x4 acc_o[2][4] = {};
    f32x4 l_acc[2] = {};

    const float c2 = 0.18033688f;   // 0.125 * log2(e)

#define ASTAGE(BUF, KK) do {                                                \
        glds16(Kgb + (size_t)((KK) * 64 + sr[0]) * QKV_N + sc[0] * 8,       \
               &Ks[BUF][t * 8]);                                            \
        glds16(Kgb + (size_t)((KK) * 64 + sr[1]) * QKV_N + sc[1] * 8,       \
               &Ks[BUF][(t + 256) * 8]);                                    \
        glds16(Vgb + (size_t)sr[0] * L_ + (KK) * 64 + sc[0] * 8,            \
               &Vs[BUF][t * 8]);                                            \
        glds16(Vgb + (size_t)sr[1] * L_ + (KK) * 64 + sc[1] * 8,            \
               &Vs[BUF][(t + 256) * 8]);                                    \
    } while (0)

    const int last = 2 * Qt + 1;

    // prologue: stage tile 0
    ASTAGE(0, 0);
    __syncthreads();   // implicit vmcnt(0): tile 0 landed + visible

    for (int kk = 0; kk <= last; ++kk) {
        const int cur = kk & 1;
        if (kk < last) ASTAGE(cur ^ 1, kk + 1);   // issue next tile early

        const bool maskedTile = (kk >= 2 * Qt);
        if (!(kk == last && w < 2)) {
            f32x4 acc_s[2][4] = {};
            __builtin_amdgcn_s_setprio(1);
            #pragma unroll
            for (int in = 0; in < 4; ++in) {
                const int key = in * 16 + l15;
                #pragma unroll
                for (int ks = 0; ks < 2; ++ks) {
                    int phys = (ks * 4 + quad) ^ (key & 7);
                    bf16x8 kf = *(const bf16x8*)&Ks[cur][key * 64 + phys * 8];
                    acc_s[0][in] = __builtin_amdgcn_mfma_f32_16x16x32_bf16(
                        qf[0][ks], kf, acc_s[0][in], 0, 0, 0);
                    acc_s[1][in] = __builtin_amdgcn_mfma_f32_16x16x32_bf16(
                        qf[1][ks], kf, acc_s[1][in], 0, 0, 0);
                }
            }
            __builtin_amdgcn_s_setprio(0);

            #pragma unroll
            for (int mt = 0; mt < 2; ++mt) {
                #pragma unroll
                for (int reg = 0; reg < 4; ++reg) {
                    const int row = mt * 16 + quad * 4 + reg;
                    float pv[4];
                    #pragma unroll
                    for (int in = 0; in < 4; ++in) {
                        float s2 = fmaf(acc_s[mt][in][reg], c2, -2.0f);
                        if (maskedTile) {
                            int col = kk * 64 + in * 16 + l15;
                            int qg  = Qt * 128 + w * 32 + row;
                            s2 = (col > qg) ? -100000.0f : s2;
                        }
                        pv[in] = __builtin_amdgcn_exp2f(s2);
                    }
                    uint_t u01 = __builtin_amdgcn_perm(
                        __float_as_uint(pv[1]), __float_as_uint(pv[0]), 0x07060302u);
                    uint_t u23 = __builtin_amdgcn_perm(
                        __float_as_uint(pv[3]), __float_as_uint(pv[2]), 0x07060302u);
                    uint2* dst = (uint2*)&Ps[w][row * 72 + l15 * 4];
                    *dst = make_uint2(u01, u23);
                }
            }

            __builtin_amdgcn_s_setprio(1);
            #pragma unroll
            for (int ks = 0; ks < 2; ++ks) {
                bf16x8 pf0 = *(const bf16x8*)&Ps[w][(l15) * 72 + ks * 32 + quad * 8];
                bf16x8 pf1 = *(const bf16x8*)&Ps[w][(16 + l15) * 72 + ks * 32 + quad * 8];
                #pragma unroll
                for (int in = 0; in < 4; ++in) {
                    const int d = in * 16 + l15;
                    int physv = (ks * 4 + quad) ^ (d & 7);
                    bf16x8 vf = *(const bf16x8*)&Vs[cur][d * 64 + physv * 8];
                    acc_o[0][in] = __builtin_amdgcn_mfma_f32_16x16x32_bf16(
                        vf, pf0, acc_o[0][in], 0, 0, 0);
                    acc_o[1][in] = __builtin_amdgcn_mfma_f32_16x16x32_bf16(
                        vf, pf1, acc_o[1][in], 0, 0, 0);
                }
                l_acc[0] = __builtin_amdgcn_mfma_f32_16x16x32_bf16(ones, pf0, l_acc[0], 0, 0, 0);
                l_acc[1] = __builtin_amdgcn_mfma_f32_16x16x32_bf16(ones, pf1, l_acc[1], 0, 0, 0);
            }
            __builtin_amdgcn_s_setprio(0);
        }

        __syncthreads();   // drains next tile's loads (flew under compute)
    }

#undef ASTAGE

    #pragma unroll
    for (int mt = 0; mt < 2; ++mt) {
        const float inv = 1.0f / l_acc[mt][0];
        const int row = b * L_ + Qt * 128 + w * 32 + mt * 16 + l15;
        #pragma unroll
        for (int in = 0; in < 4; ++in) {
            const int dbase = h * DH_ + in * 16 + quad * 4;
            f32x4 a = acc_o[mt][in];
            ushort4 o;
            o.x = f2bf(a[0] * inv); o.y = f2bf(a[1] * inv);
            o.z = f2bf(a[2] * inv); o.w = f2bf(a[3] * inv);
            *(ushort4*)(Zb + (size_t)row * D_ + dbase) = o;
        }
    }
}

// ---------------------------------------------------------------------------
// LayerNorm over last dim (1024), bf16 input, fp32 out. 256-thread blocks,
// 4 rows per block (one row per wave; shuffles are wave-local).
// ---------------------------------------------------------------------------
__global__ __launch_bounds__(256) void ln_kernel(const ushort_t* __restrict__ Y,
                                                 const float* __restrict__ gamma,
                                                 const float* __restrict__ beta,
                                                 float* __restrict__ out) {
    const int row = blockIdx.x * 4 + (threadIdx.x >> 6);
    const int t = threadIdx.x & 63;
    const ushort_t* y = Y + (size_t)row * D_;

    float v[16];
    #pragma unroll
    for (int s = 0; s < 4; ++s) {
        ushort4 u = *(const ushort4*)(y + s * 256 + t * 4);
        v[s * 4 + 0] = bf2f(u.x);
        v[s * 4 + 1] = bf2f(u.y);
        v[s * 4 + 2] = bf2f(u.z);
        v[s * 4 + 3] = bf2f(u.w);
    }

    float sum = 0.f;
    #pragma unroll
    for (int i = 0; i < 16; ++i) sum += v[i];
    #pragma unroll
    for (int k = 1; k < 64; k <<= 1) sum += __shfl_xor(sum, k, 64);
    const float mu = sum * (1.f / (float)D_);

    float var = 0.f;
    #pragma unroll
    for (int i = 0; i < 16; ++i) {
        float d = v[i] - mu;
        var += d * d;
    }
    #pragma unroll
    for (int k = 1; k < 64; k <<= 1) var += __shfl_xor(var, k, 64);
    const float rstd = rsqrtf(var * (1.f / (float)D_) + 1e-12f);

    #pragma unroll
    for (int s = 0; s < 4; ++s) {
        const int col = s * 256 + t * 4;
        float4 g  = *(const float4*)(gamma + col);
        float4 bb = *(const float4*)(beta + col);
        float4 o;
        o.x = (v[s * 4 + 0] - mu) * rstd * g.x + bb.x;
        o.y = (v[s * 4 + 1] - mu) * rstd * g.y + bb.y;
        o.z = (v[s * 4 + 2] - mu) * rstd * g.z + bb.z;
        o.w = (v[s * 4 + 3] - mu) * rstd * g.w + bb.w;
        *(float4*)(out + (size_t)row * D_ + col) = o;
    }
}

// ---------------------------------------------------------------------------
extern "C" void kernel_launch(void* const* d_in, const int* in_sizes, int n_in,
                              void* d_out, int out_size, void* d_ws, size_t ws_size,
                              hipStream_t stream) {
    const float* x     = (const float*)d_in[0];
    const float* Wq    = (const float*)d_in[1];
    const float* Wk    = (const float*)d_in[2];
    const float* Wv    = (const float*)d_in[3];
    const float* Wo    = (const float*)d_in[4];
    const float* gamma = (const float*)d_in[5];
    const float* beta  = (const float*)d_in[6];
    float* out = (float*)d_out;

    char* ws = (char*)d_ws;
    ushort_t* x_bf = (ushort_t*)(ws);                 // 16 MB
    ushort_t* wcat = (ushort_t*)(ws + (16u  << 20));  //  6 MB (Wq^T|Wk^T|Wv^T)
    ushort_t* wto  = (ushort_t*)(ws + (22u  << 20));  //  2 MB
    ushort_t* qkv  = (ushort_t*)(ws + (24u  << 20));  // 48 MB [8192][3072] (V region unused)
    ushort_t* vt   = (ushort_t*)(ws + (72u  << 20));  // 16 MB
    ushort_t* z_bf = (ushort_t*)(ws + (88u  << 20));  // 16 MB
    ushort_t* y_bf = (ushort_t*)(ws + (104u << 20));  // 16 MB

    const int M = B_ * L_;

    prep<<<dim3(16, 16, 5), 256, 0, stream>>>(Wq, Wk, Wv, Wo, x, wcat, wto, x_bf);

    // QKV: 256x128-tile 8-phase, 768 blocks = 3.0 exact rounds (round-5
    // schedule, best measured: 63.8 us)
    gemm8p<<<dim3(QKV_N / 128, M / 256), 512, 0, stream>>>(
        x_bf, wcat, qkv, nullptr, vt, M, QKV_N, D_, 0);

    // attn: 64-key tiles, double-buffered K/V with stage-ahead-1 (round-8)
    attn_mfma<<<dim3(B_ * H_, 16), 256, 0, stream>>>(qkv, vt, z_bf);

    // out-proj: 128^2, 512 blocks at 3-4/CU (inter-block overlap regime)
    gemm_mfma<<<dim3(D_ / 128, M / 128), 256, 0, stream>>>(
        z_bf, wto, y_bf, x_bf, nullptr, M, D_, D_, 1);

    ln_kernel<<<M / 4, 256, 0, stream>>>(y_bf, gamma, beta, out);
}

// Round 9
// 281.626 us; speedup vs baseline: 1.0196x; 1.0196x over previous
//
#include <hip/hip_runtime.h>
#include <math.h>

#define B_ 4
#define L_ 2048
#define D_ 1024
#define H_ 16
#define DH_ 64
#define QKV_N 3072

typedef unsigned short ushort_t;
typedef unsigned int uint_t;
using bf16x8 = __attribute__((ext_vector_type(8))) short;
using f32x4  = __attribute__((ext_vector_type(4))) float;

__device__ __forceinline__ ushort_t f2bf(float f) {
    union { float f; unsigned int u; } v; v.f = f;
    unsigned int u = v.u;
    unsigned int rnd = ((u >> 16) & 1u) + 0x7fffu;
    return (ushort_t)((u + rnd) >> 16);
}

__device__ __forceinline__ float bf2f(ushort_t u) {
    union { unsigned int u; float f; } v;
    v.u = ((unsigned int)u) << 16;
    return v.f;
}

__device__ __forceinline__ void glds16(const void* g, void* l) {
    __builtin_amdgcn_global_load_lds(
        (const __attribute__((address_space(1))) unsigned int*)g,
        (__attribute__((address_space(3))) unsigned int*)l, 16, 0, 0);
}

// ---------------------------------------------------------------------------
// prep: blockIdx.z<4 -> transpose weight z into bf16 [n][k]; z==4 -> cast x.
// ---------------------------------------------------------------------------
__global__ __launch_bounds__(256) void prep(const float* __restrict__ Wq,
                                            const float* __restrict__ Wk,
                                            const float* __restrict__ Wv,
                                            const float* __restrict__ Wo,
                                            const float* __restrict__ x,
                                            ushort_t* __restrict__ wcat,
                                            ushort_t* __restrict__ wto,
                                            ushort_t* __restrict__ xb) {
    const int t = threadIdx.x;
    if (blockIdx.z == 4) {
        const int bid = blockIdx.y * 16 + blockIdx.x;
        const int base = bid * 32768 + t * 4;
        #pragma unroll
        for (int it = 0; it < 32; ++it) {
            float4 v = *(const float4*)(x + base + it * 1024);
            ushort4 o;
            o.x = f2bf(v.x); o.y = f2bf(v.y); o.z = f2bf(v.z); o.w = f2bf(v.w);
            *(ushort4*)(xb + base + it * 1024) = o;
        }
        return;
    }
    __shared__ ushort_t tile[64][65];
    const int widx = blockIdx.z;
    const float* W = (widx == 0) ? Wq : (widx == 1) ? Wk : (widx == 2) ? Wv : Wo;
    ushort_t* dst = (widx < 3) ? (wcat + (size_t)widx * 1024 * 1024) : wto;
    const int j = t & 63, i0 = t >> 6;
    const int kbase = blockIdx.y * 64, nbase = blockIdx.x * 64;
    #pragma unroll
    for (int it = 0; it < 16; ++it) {
        int i = it * 4 + i0;
        tile[i][j] = f2bf(W[(size_t)(kbase + i) * 1024 + nbase + j]);
    }
    __syncthreads();
    #pragma unroll
    for (int it = 0; it < 16; ++it) {
        int nn = it * 4 + i0;
        dst[(size_t)(nbase + nn) * 1024 + kbase + j] = tile[j][nn];
    }
}

// ---------------------------------------------------------------------------
// 256x128-tile 8-phase GEMM (T3+T4+T5), BK=64 in two 32-wide k-halves.
// QKV only: 768 blocks = 3.0 exact rounds at 1 block/CU (96 KiB LDS).
// Round-5 schedule == best measured (63.8 us, 807 TF, MfmaUtil 32.5%).
// Round-6's phase-merge REGRESSED (75.1 us) — m196 confirmed: do not
// merge phases. Waits: every full phase ends vmcnt(6); peeled epilogue
// drains 6 -> 3 -> 0.
// ---------------------------------------------------------------------------
__global__ __launch_bounds__(512) void gemm8p(const ushort_t* __restrict__ A,
                                              const ushort_t* __restrict__ Wt,
                                              ushort_t* __restrict__ Cbf,
                                              const ushort_t* __restrict__ resid,
                                              ushort_t* __restrict__ vt,
                                              int M, int N, int K, int fuse) {
    __shared__ ushort_t lds[49152];  // [buf]*24576 + [kh]*12288 + {A:0|B:8192}
    const int t = threadIdx.x;
    const int w = t >> 6, ln = t & 63;
    const int l15 = ln & 15, quad = ln >> 4;
    const int wrow = w >> 1, wcol = w & 1;

    // XCD-aware bijective block swizzle (grid has nwg % 8 == 0)
    int bx = blockIdx.x, by = blockIdx.y;
    {
        int nwg = gridDim.x * gridDim.y;
        if ((nwg & 7) == 0) {
            int flat = by * gridDim.x + bx;
            int nid = (flat & 7) * (nwg >> 3) + (flat >> 3);
            by = nid / gridDim.x;
            bx = nid - by * gridDim.x;
        }
    }
    const int bm = by * 256, bn = bx * 128;

    // staging source pointers (pre-swizzled global addresses)
    const ushort_t* Agp[2];
    const ushort_t* Bgp;
    #pragma unroll
    for (int j = 0; j < 2; ++j) {
        int r = j * 128 + (t >> 2);
        int c = (t & 3) ^ ((r >> 1) & 3);
        Agp[j] = A + (size_t)(bm + r) * K + c * 8;
    }
    {
        int r = t >> 2;
        int c = (t & 3) ^ ((r >> 1) & 3);
        Bgp = Wt + (size_t)(bn + r) * K + c * 8;
    }

    const int swz8 = (quad ^ ((l15 >> 1) & 3)) * 8;
    int aoff[4], boff[4];
    #pragma unroll
    for (int mf = 0; mf < 4; ++mf)
        aoff[mf] = (wrow * 64 + mf * 16 + l15) * 32 + swz8;
    #pragma unroll
    for (int nf = 0; nf < 4; ++nf)
        boff[nf] = (wcol * 64 + nf * 16 + l15) * 32 + swz8;

    f32x4 acc[4][4] = {};
    const int NT = K >> 6;

#define ABASE(BUF, KH) ((BUF) * 24576 + (KH) * 12288)
#define BBASE(BUF, KH) (ABASE(BUF, KH) + 8192)

#define STAGE(BUF, KH, KT) do {                                             \
        glds16(Agp[0] + (KT) * 64 + (KH) * 32, &lds[ABASE(BUF, KH) + t * 8]);\
        glds16(Agp[1] + (KT) * 64 + (KH) * 32,                              \
               &lds[ABASE(BUF, KH) + 4096 + t * 8]);                        \
        glds16(Bgp + (KT) * 64 + (KH) * 32, &lds[BBASE(BUF, KH) + t * 8]);  \
    } while (0)

#define VM6 asm volatile("s_waitcnt vmcnt(6)" ::: "memory")
#define VM3 asm volatile("s_waitcnt vmcnt(3)" ::: "memory")
#define VM0 asm volatile("s_waitcnt vmcnt(0)" ::: "memory")
#define NOVM ((void)0)

#define PHASE(BUF, KH, STAGEC, VMW) do {                                    \
        bf16x8 af_[4], bf_[4];                                              \
        _Pragma("unroll")                                                   \
        for (int m_ = 0; m_ < 4; ++m_)                                      \
            af_[m_] = *(const bf16x8*)&lds[ABASE(BUF, KH) + aoff[m_]];      \
        _Pragma("unroll")                                                   \
        for (int n_ = 0; n_ < 4; ++n_)                                      \
            bf_[n_] = *(const bf16x8*)&lds[BBASE(BUF, KH) + boff[n_]];      \
        STAGEC;                                                             \
        VMW;                                                                \
        __builtin_amdgcn_s_barrier();                                       \
        asm volatile("s_waitcnt lgkmcnt(0)" ::: "memory");                  \
        __builtin_amdgcn_s_setprio(1);                                      \
        _Pragma("unroll")                                                   \
        for (int m_ = 0; m_ < 4; ++m_)                                      \
            _Pragma("unroll")                                               \
            for (int n_ = 0; n_ < 4; ++n_)                                  \
                acc[m_][n_] = __builtin_amdgcn_mfma_f32_16x16x32_bf16(      \
                    af_[m_], bf_[n_], acc[m_][n_], 0, 0, 0);                \
        __builtin_amdgcn_s_setprio(0);                                      \
        __builtin_amdgcn_s_barrier();                                       \
    } while (0)

    // prologue: S1=b0k0(t0), S2=b0k1(t0), S3=b1k0(t1); 9 loads.
    STAGE(0, 0, 0);
    STAGE(0, 1, 0);
    STAGE(1, 0, 1);
    VM6;
    __builtin_amdgcn_s_barrier();

    // full iterations: every phase stages, every phase ends vmcnt(6)
    for (int it = 0; it < (NT >> 1) - 1; ++it) {
        const int kt1 = 2 * it + 1, kt2 = 2 * it + 2, kt3 = 2 * it + 3;
        PHASE(0, 0, STAGE(1, 1, kt1), VM6);
        PHASE(0, 1, STAGE(0, 0, kt2), VM6);
        PHASE(1, 0, STAGE(0, 1, kt2), VM6);
        PHASE(1, 1, STAGE(1, 0, kt3), VM6);
    }

    // peeled final iteration: drain 6 -> 3 -> 0.
    PHASE(0, 0, STAGE(1, 1, NT - 1), VM6);
    PHASE(0, 1, NOVM, VM3);
    PHASE(1, 0, NOVM, VM0);
    PHASE(1, 1, NOVM, NOVM);

#undef PHASE
#undef STAGE
#undef ABASE
#undef BBASE

    if (vt && bn >= 2048) {
        #pragma unroll
        for (int mf = 0; mf < 4; ++mf) {
            #pragma unroll
            for (int nf = 0; nf < 4; ++nf) {
                #pragma unroll
                for (int reg = 0; reg < 4; ++reg) {
                    int row = bm + wrow * 64 + mf * 16 + quad * 4 + reg;
                    int col = bn + wcol * 64 + nf * 16 + l15 - 2048;
                    int bb = row >> 11, tok = row & 2047;
                    int h = col >> 6, d = col & 63;
                    int tg = tok & 63;
                    int sc = (tg & 15) * 4 + (tg >> 4);
                    size_t addr = ((size_t)((bb * 16 + h) * 64 + d) << 11)
                                + (tok & ~63) + sc;
                    vt[addr] = f2bf(acc[mf][nf][reg]);
                }
            }
        }
    } else {
        #pragma unroll
        for (int mf = 0; mf < 4; ++mf) {
            #pragma unroll
            for (int nf = 0; nf < 4; ++nf) {
                #pragma unroll
                for (int reg = 0; reg < 4; ++reg) {
                    int row = bm + wrow * 64 + mf * 16 + quad * 4 + reg;
                    int col = bn + wcol * 64 + nf * 16 + l15;
                    size_t idx = (size_t)row * N + col;
                    float v = acc[mf][nf][reg];
                    if (fuse) v = fmaxf(v, 0.f) + bf2f(resid[idx]);
                    Cbf[idx] = f2bf(v);
                }
            }
        }
    }
}

// ---------------------------------------------------------------------------
// bf16 MFMA GEMM, tile 128x128, BK=64. Used for out-proj: 512 blocks at
// 3-4 blocks/CU — inter-block overlap hides prologue/epilogue (the 8-phase
// variant at 1.0 rounds lost 14 us to exposed tails, round-3 post-mortem).
// ---------------------------------------------------------------------------
__global__ __launch_bounds__(256) void gemm_mfma(const ushort_t* __restrict__ A,
                                                 const ushort_t* __restrict__ Wt,
                                                 ushort_t* __restrict__ Cbf,
                                                 const ushort_t* __restrict__ resid,
                                                 ushort_t* __restrict__ vt,
                                                 int M, int N, int K, int fuse) {
    __shared__ ushort_t As[128 * 64];
    __shared__ ushort_t Bs[128 * 64];
    const int t = threadIdx.x;
    const int w = t >> 6, ln = t & 63;
    const int l15 = ln & 15, quad = ln >> 4;
    const int bm = blockIdx.y * 128, bn = blockIdx.x * 128;
    const int wm = (w & 1) * 64, wn = (w >> 1) * 64;

    const ushort_t* Ap[4];
    const ushort_t* Bp[4];
    #pragma unroll
    for (int j = 0; j < 4; ++j) {
        const int i = t + j * 256;
        const int r = i >> 3;
        const int qg = (i & 7) ^ (r & 7);
        Ap[j] = A  + (size_t)(bm + r) * K + qg * 8;
        Bp[j] = Wt + (size_t)(bn + r) * K + qg * 8;
    }

    f32x4 acc[4][4] = {};

    for (int k0 = 0; k0 < K; k0 += 64) {
        __syncthreads();
        #pragma unroll
        for (int j = 0; j < 4; ++j) {
            glds16(Ap[j] + k0, &As[(t + j * 256) * 8]);
            glds16(Bp[j] + k0, &Bs[(t + j * 256) * 8]);
        }
        __syncthreads();

        #pragma unroll
        for (int kw = 0; kw < 2; ++kw) {
            bf16x8 af[4], bfr[4];
            #pragma unroll
            for (int im = 0; im < 4; ++im) {
                int row = wm + im * 16 + l15;
                int phys = (kw * 4 + quad) ^ (row & 7);
                af[im] = *(const bf16x8*)&As[row * 64 + phys * 8];
            }
            #pragma unroll
            for (int in = 0; in < 4; ++in) {
                int row = wn + in * 16 + l15;
                int phys = (kw * 4 + quad) ^ (row & 7);
                bfr[in] = *(const bf16x8*)&Bs[row * 64 + phys * 8];
            }
            #pragma unroll
            for (int im = 0; im < 4; ++im)
                #pragma unroll
                for (int in = 0; in < 4; ++in)
                    acc[im][in] = __builtin_amdgcn_mfma_f32_16x16x32_bf16(
                        af[im], bfr[in], acc[im][in], 0, 0, 0);
        }
    }

    if (vt && bn >= 2048) {
        #pragma unroll
        for (int im = 0; im < 4; ++im) {
            #pragma unroll
            for (int in = 0; in < 4; ++in) {
                #pragma unroll
                for (int reg = 0; reg < 4; ++reg) {
                    int row = bm + wm + im * 16 + quad * 4 + reg;
                    int col = bn + wn + in * 16 + l15 - 2048;
                    int bb = row >> 11, tok = row & 2047;
                    int h = col >> 6, d = col & 63;
                    int tg = tok & 63;
                    int sc = (tg & 15) * 4 + (tg >> 4);
                    size_t addr = ((size_t)((bb * 16 + h) * 64 + d) << 11)
                                + (tok & ~63) + sc;
                    vt[addr] = f2bf(acc[im][in][reg]);
                }
            }
        }
    } else {
        #pragma unroll
        for (int im = 0; im < 4; ++im) {
            #pragma unroll
            for (int in = 0; in < 4; ++in) {
                #pragma unroll
                for (int reg = 0; reg < 4; ++reg) {
                    int row = bm + wm + im * 16 + quad * 4 + reg;
                    int col = bn + wn + in * 16 + l15;
                    size_t idx = (size_t)row * N + col;
                    float v = acc[im][in][reg];
                    if (fuse) v = fmaxf(v, 0.f) + bf2f(resid[idx]);
                    Cbf[idx] = f2bf(v);
                }
            }
        }
    }
}

// ---------------------------------------------------------------------------
// Flash attention, bf16 MFMA, static-max softmax. Block = 4 waves, 128
// queries (wave w: 32). 128-key K/V tiles, PV in two 64-key phases reusing
// wave-private Ps. Round-8's 64-key stage-ahead pipeline REGRESSED
// (72.3 us, 1.08M LDS bank conflicts from glds write-backs contending
// with ds_reads, VALUBusy 57% from doubled iterations) — reverted to the
// dedicated-staging-window structure (0 conflicts, <64 us).
// Grid (64 bh, 16): Qt = 15 - blockIdx.y (LPT dispatch).
// T5: s_setprio(1) around the QK^T and PV MFMA clusters.
// ---------------------------------------------------------------------------
__global__ __launch_bounds__(256) void attn_mfma(const ushort_t* __restrict__ qkv,
                                                 const ushort_t* __restrict__ Vt,
                                                 ushort_t* __restrict__ Zb) {
    __shared__ ushort_t Ks[128 * 64];
    __shared__ ushort_t Vs[64 * 128];
    __shared__ ushort_t Ps[4][32 * 72];
    const int t = threadIdx.x, w = t >> 6, ln = t & 63;
    const int l15 = ln & 15, quad = ln >> 4;
    const int bh = blockIdx.x;
    const int b = bh >> 4, h = bh & 15;
    const int Qt = 15 - blockIdx.y;

    bf16x8 ones;
    #pragma unroll
    for (int i = 0; i < 8; ++i) ones[i] = (short)0x3f80;

    int kkey[4], kq[4], vd[4], vcq[4];
    #pragma unroll
    for (int j = 0; j < 4; ++j) {
        int i = t + j * 256;
        kkey[j] = i >> 3;
        kq[j]   = (i & 7) ^ (kkey[j] & 7);
        vd[j]   = i >> 4;
        int cqp = i & 15;
        vcq[j]  = (cqp & 8) | ((cqp & 7) ^ (vd[j] & 7));
    }
    const ushort_t* Kgb = qkv + 1024 + (size_t)b * L_ * QKV_N + h * DH_;
    const ushort_t* Vgb = Vt + (size_t)((b * H_ + h) * DH_) * L_;

    bf16x8 qf[2][2];
    #pragma unroll
    for (int mt = 0; mt < 2; ++mt) {
        const ushort_t* qrow =
            qkv + (size_t)(b * L_ + Qt * 128 + w * 32 + mt * 16 + l15) * QKV_N + h * DH_;
        qf[mt][0] = *(const bf16x8*)(qrow + quad * 8);
        qf[mt][1] = *(const bf16x8*)(qrow + 32 + quad * 8);
    }

    f32x4 acc_o[2][4] = {};
    f32x4 l_acc[2] = {};

    const float c2 = 0.18033688f;   // 0.125 * log2(e)

    for (int kt = 0; kt <= Qt; ++kt) {
        __syncthreads();
        #pragma unroll
        for (int j = 0; j < 4; ++j) {
            glds16(Kgb + (size_t)(kt * 128 + kkey[j]) * QKV_N + kq[j] * 8,
                   &Ks[(t + j * 256) * 8]);
            glds16(Vgb + (size_t)vd[j] * L_ + kt * 128 + vcq[j] * 8,
                   &Vs[(t + j * 256) * 8]);
        }
        __syncthreads();

        const bool masked = (kt == Qt);

        #pragma unroll
        for (int ph = 0; ph < 2; ++ph) {
            if (masked && ph && w < 2) continue;

            f32x4 acc_s[2][4] = {};
            __builtin_amdgcn_s_setprio(1);
            #pragma unroll
            for (int in = 0; in < 4; ++in) {
                const int key = ph * 64 + in * 16 + l15;
                #pragma unroll
                for (int ks = 0; ks < 2; ++ks) {
                    int phys = (ks * 4 + quad) ^ (key & 7);
                    bf16x8 kf = *(const bf16x8*)&Ks[key * 64 + phys * 8];
                    acc_s[0][in] = __builtin_amdgcn_mfma_f32_16x16x32_bf16(
                        qf[0][ks], kf, acc_s[0][in], 0, 0, 0);
                    acc_s[1][in] = __builtin_amdgcn_mfma_f32_16x16x32_bf16(
                        qf[1][ks], kf, acc_s[1][in], 0, 0, 0);
                }
            }
            __builtin_amdgcn_s_setprio(0);

            #pragma unroll
            for (int mt = 0; mt < 2; ++mt) {
                #pragma unroll
                for (int reg = 0; reg < 4; ++reg) {
                    const int row = mt * 16 + quad * 4 + reg;
                    float pv[4];
                    #pragma unroll
                    for (int in = 0; in < 4; ++in) {
                        float s2 = fmaf(acc_s[mt][in][reg], c2, -2.0f);
                        if (masked) {
                            int col = kt * 128 + ph * 64 + in * 16 + l15;
                            int qg  = Qt * 128 + w * 32 + row;
                            s2 = (col > qg) ? -100000.0f : s2;
                        }
                        pv[in] = __builtin_amdgcn_exp2f(s2);
                    }
                    uint_t u01 = __builtin_amdgcn_perm(
                        __float_as_uint(pv[1]), __float_as_uint(pv[0]), 0x07060302u);
                    uint_t u23 = __builtin_amdgcn_perm(
                        __float_as_uint(pv[3]), __float_as_uint(pv[2]), 0x07060302u);
                    uint2* dst = (uint2*)&Ps[w][row * 72 + l15 * 4];
                    *dst = make_uint2(u01, u23);
                }
            }

            __builtin_amdgcn_s_setprio(1);
            #pragma unroll
            for (int ks = 0; ks < 2; ++ks) {
                bf16x8 pf0 = *(const bf16x8*)&Ps[w][(l15) * 72 + ks * 32 + quad * 8];
                bf16x8 pf1 = *(const bf16x8*)&Ps[w][(16 + l15) * 72 + ks * 32 + quad * 8];
                #pragma unroll
                for (int in = 0; in < 4; ++in) {
                    const int d = in * 16 + l15;
                    int physv = ph * 8 + (((ks * 4 + quad) ^ (d & 7)));
                    bf16x8 vf = *(const bf16x8*)&Vs[d * 128 + physv * 8];
                    acc_o[0][in] = __builtin_amdgcn_mfma_f32_16x16x32_bf16(
                        vf, pf0, acc_o[0][in], 0, 0, 0);
                    acc_o[1][in] = __builtin_amdgcn_mfma_f32_16x16x32_bf16(
                        vf, pf1, acc_o[1][in], 0, 0, 0);
                }
                l_acc[0] = __builtin_amdgcn_mfma_f32_16x16x32_bf16(ones, pf0, l_acc[0], 0, 0, 0);
                l_acc[1] = __builtin_amdgcn_mfma_f32_16x16x32_bf16(ones, pf1, l_acc[1], 0, 0, 0);
            }
            __builtin_amdgcn_s_setprio(0);
        }
    }

    #pragma unroll
    for (int mt = 0; mt < 2; ++mt) {
        const float inv = 1.0f / l_acc[mt][0];
        const int row = b * L_ + Qt * 128 + w * 32 + mt * 16 + l15;
        #pragma unroll
        for (int in = 0; in < 4; ++in) {
            const int dbase = h * DH_ + in * 16 + quad * 4;
            f32x4 a = acc_o[mt][in];
            ushort4 o;
            o.x = f2bf(a[0] * inv); o.y = f2bf(a[1] * inv);
            o.z = f2bf(a[2] * inv); o.w = f2bf(a[3] * inv);
            *(ushort4*)(Zb + (size_t)row * D_ + dbase) = o;
        }
    }
}

// ---------------------------------------------------------------------------
// LayerNorm over last dim (1024), bf16 input, fp32 out. 256-thread blocks,
// 4 rows per block (one row per wave; shuffles are wave-local).
// ---------------------------------------------------------------------------
__global__ __launch_bounds__(256) void ln_kernel(const ushort_t* __restrict__ Y,
                                                 const float* __restrict__ gamma,
                                                 const float* __restrict__ beta,
                                                 float* __restrict__ out) {
    const int row = blockIdx.x * 4 + (threadIdx.x >> 6);
    const int t = threadIdx.x & 63;
    const ushort_t* y = Y + (size_t)row * D_;

    float v[16];
    #pragma unroll
    for (int s = 0; s < 4; ++s) {
        ushort4 u = *(const ushort4*)(y + s * 256 + t * 4);
        v[s * 4 + 0] = bf2f(u.x);
        v[s * 4 + 1] = bf2f(u.y);
        v[s * 4 + 2] = bf2f(u.z);
        v[s * 4 + 3] = bf2f(u.w);
    }

    float sum = 0.f;
    #pragma unroll
    for (int i = 0; i < 16; ++i) sum += v[i];
    #pragma unroll
    for (int k = 1; k < 64; k <<= 1) sum += __shfl_xor(sum, k, 64);
    const float mu = sum * (1.f / (float)D_);

    float var = 0.f;
    #pragma unroll
    for (int i = 0; i < 16; ++i) {
        float d = v[i] - mu;
        var += d * d;
    }
    #pragma unroll
    for (int k = 1; k < 64; k <<= 1) var += __shfl_xor(var, k, 64);
    const float rstd = rsqrtf(var * (1.f / (float)D_) + 1e-12f);

    #pragma unroll
    for (int s = 0; s < 4; ++s) {
        const int col = s * 256 + t * 4;
        float4 g  = *(const float4*)(gamma + col);
        float4 bb = *(const float4*)(beta + col);
        float4 o;
        o.x = (v[s * 4 + 0] - mu) * rstd * g.x + bb.x;
        o.y = (v[s * 4 + 1] - mu) * rstd * g.y + bb.y;
        o.z = (v[s * 4 + 2] - mu) * rstd * g.z + bb.z;
        o.w = (v[s * 4 + 3] - mu) * rstd * g.w + bb.w;
        *(float4*)(out + (size_t)row * D_ + col) = o;
    }
}

// ---------------------------------------------------------------------------
extern "C" void kernel_launch(void* const* d_in, const int* in_sizes, int n_in,
                              void* d_out, int out_size, void* d_ws, size_t ws_size,
                              hipStream_t stream) {
    const float* x     = (const float*)d_in[0];
    const float* Wq    = (const float*)d_in[1];
    const float* Wk    = (const float*)d_in[2];
    const float* Wv    = (const float*)d_in[3];
    const float* Wo    = (const float*)d_in[4];
    const float* gamma = (const float*)d_in[5];
    const float* beta  = (const float*)d_in[6];
    float* out = (float*)d_out;

    char* ws = (char*)d_ws;
    ushort_t* x_bf = (ushort_t*)(ws);                 // 16 MB
    ushort_t* wcat = (ushort_t*)(ws + (16u  << 20));  //  6 MB (Wq^T|Wk^T|Wv^T)
    ushort_t* wto  = (ushort_t*)(ws + (22u  << 20));  //  2 MB
    ushort_t* qkv  = (ushort_t*)(ws + (24u  << 20));  // 48 MB [8192][3072] (V region unused)
    ushort_t* vt   = (ushort_t*)(ws + (72u  << 20));  // 16 MB
    ushort_t* z_bf = (ushort_t*)(ws + (88u  << 20));  // 16 MB
    ushort_t* y_bf = (ushort_t*)(ws + (104u << 20));  // 16 MB

    const int M = B_ * L_;

    prep<<<dim3(16, 16, 5), 256, 0, stream>>>(Wq, Wk, Wv, Wo, x, wcat, wto, x_bf);

    // QKV: 256x128-tile 8-phase, 768 blocks = 3.0 exact rounds (round-5
    // schedule, best measured: 63.8 us)
    gemm8p<<<dim3(QKV_N / 128, M / 256), 512, 0, stream>>>(
        x_bf, wcat, qkv, nullptr, vt, M, QKV_N, D_, 0);

    // attn: 128-key tiles, dedicated staging window (round-7 best; round-8
    // pipeline reverted — bank-conflict + iteration-overhead regression)
    attn_mfma<<<dim3(B_ * H_, 16), 256, 0, stream>>>(qkv, vt, z_bf);

    // out-proj: 128^2, 512 blocks at 3-4/CU (inter-block overlap regime)
    gemm_mfma<<<dim3(D_ / 128, M / 128), 256, 0, stream>>>(
        z_bf, wto, y_bf, x_bf, nullptr, M, D_, D_, 1);

    ln_kernel<<<M / 4, 256, 0, stream>>>(y_bf, gamma, beta, out);
}

// Round 10
// 269.286 us; speedup vs baseline: 1.0663x; 1.0458x over previous
//
#include <hip/hip_runtime.h>
#include <math.h>

#define B_ 4
#define L_ 2048
#define D_ 1024
#define H_ 16
#define DH_ 64
#define QKV_N 3072

typedef unsigned short ushort_t;
typedef unsigned int uint_t;
using bf16x8 = __attribute__((ext_vector_type(8))) short;
using f32x4  = __attribute__((ext_vector_type(4))) float;

__device__ __forceinline__ ushort_t f2bf(float f) {
    union { float f; unsigned int u; } v; v.f = f;
    unsigned int u = v.u;
    unsigned int rnd = ((u >> 16) & 1u) + 0x7fffu;
    return (ushort_t)((u + rnd) >> 16);
}

__device__ __forceinline__ float bf2f(ushort_t u) {
    union { unsigned int u; float f; } v;
    v.u = ((unsigned int)u) << 16;
    return v.f;
}

__device__ __forceinline__ void glds16(const void* g, void* l) {
    __builtin_amdgcn_global_load_lds(
        (const __attribute__((address_space(1))) unsigned int*)g,
        (__attribute__((address_space(3))) unsigned int*)l, 16, 0, 0);
}

// ---------------------------------------------------------------------------
// prep: blockIdx.z<4 -> transpose weight z into bf16 [n][k]; z==4 -> cast x.
// ---------------------------------------------------------------------------
__global__ __launch_bounds__(256) void prep(const float* __restrict__ Wq,
                                            const float* __restrict__ Wk,
                                            const float* __restrict__ Wv,
                                            const float* __restrict__ Wo,
                                            const float* __restrict__ x,
                                            ushort_t* __restrict__ wcat,
                                            ushort_t* __restrict__ wto,
                                            ushort_t* __restrict__ xb) {
    const int t = threadIdx.x;
    if (blockIdx.z == 4) {
        const int bid = blockIdx.y * 16 + blockIdx.x;
        const int base = bid * 32768 + t * 4;
        #pragma unroll
        for (int it = 0; it < 32; ++it) {
            float4 v = *(const float4*)(x + base + it * 1024);
            ushort4 o;
            o.x = f2bf(v.x); o.y = f2bf(v.y); o.z = f2bf(v.z); o.w = f2bf(v.w);
            *(ushort4*)(xb + base + it * 1024) = o;
        }
        return;
    }
    __shared__ ushort_t tile[64][65];
    const int widx = blockIdx.z;
    const float* W = (widx == 0) ? Wq : (widx == 1) ? Wk : (widx == 2) ? Wv : Wo;
    ushort_t* dst = (widx < 3) ? (wcat + (size_t)widx * 1024 * 1024) : wto;
    const int j = t & 63, i0 = t >> 6;
    const int kbase = blockIdx.y * 64, nbase = blockIdx.x * 64;
    #pragma unroll
    for (int it = 0; it < 16; ++it) {
        int i = it * 4 + i0;
        tile[i][j] = f2bf(W[(size_t)(kbase + i) * 1024 + nbase + j]);
    }
    __syncthreads();
    #pragma unroll
    for (int it = 0; it < 16; ++it) {
        int nn = it * 4 + i0;
        dst[(size_t)(nbase + nn) * 1024 + kbase + j] = tile[j][nn];
    }
}

// ---------------------------------------------------------------------------
// 256x128-tile pipelined GEMM, 32-wide k-steps, 3-region LDS ring (72 KiB)
// -> 2 blocks/CU (round-10). Phase body identical to the proven r5 8-phase
// (8 ds_read + 3 glds + counted wait + barrier + lgkm + 16 MFMA — the fine
// interleave m196 requires); changes are only: regions 4 -> 3, per-phase
// wait vmcnt(6) -> vmcnt(3), runtime region bases rotated mod 3.
// Rationale: at 1 block/CU every stall is exposed; 2 blocks/CU fills
// stalls with the co-resident block's MFMA (out-proj evidence). Trade:
// stage->consume slack ~2 phases -> ~1.
// Ring: phase s reads region s%3; stages step s+2 into region (s-1)%3.
// WAR: phase s-1's reads (all waves) drain via per-wave lgkmcnt(0) before
// its end-barrier, which precedes phase s's glds issue. RAW: end-of-phase
// vmcnt(3) leaves only the newest region (S_{s+2}) in flight -> S_{s+1}
// landed + barrier-visible one phase before consumption. Epilogue:
// VM0 -> none. Region layout (ushort): A[0,8192) B[8192,12288), row
// stride 32, chunk swizzle phys = logical ^ ((row>>1)&3) via pre-swizzled
// global source.
// ---------------------------------------------------------------------------
__global__ __launch_bounds__(512) void gemm8p(const ushort_t* __restrict__ A,
                                              const ushort_t* __restrict__ Wt,
                                              ushort_t* __restrict__ Cbf,
                                              const ushort_t* __restrict__ resid,
                                              ushort_t* __restrict__ vt,
                                              int M, int N, int K, int fuse) {
    __shared__ ushort_t lds[36864];  // 3 regions x 12288 ushorts = 72 KiB
    const int t = threadIdx.x;
    const int w = t >> 6, ln = t & 63;
    const int l15 = ln & 15, quad = ln >> 4;
    const int wrow = w >> 1, wcol = w & 1;

    // XCD-aware bijective block swizzle (grid has nwg % 8 == 0)
    int bx = blockIdx.x, by = blockIdx.y;
    {
        int nwg = gridDim.x * gridDim.y;
        if ((nwg & 7) == 0) {
            int flat = by * gridDim.x + bx;
            int nid = (flat & 7) * (nwg >> 3) + (flat >> 3);
            by = nid / gridDim.x;
            bx = nid - by * gridDim.x;
        }
    }
    const int bm = by * 256, bn = bx * 128;

    // staging source pointers (pre-swizzled global addresses)
    const ushort_t* Agp[2];
    const ushort_t* Bgp;
    #pragma unroll
    for (int j = 0; j < 2; ++j) {
        int r = j * 128 + (t >> 2);
        int c = (t & 3) ^ ((r >> 1) & 3);
        Agp[j] = A + (size_t)(bm + r) * K + c * 8;
    }
    {
        int r = t >> 2;
        int c = (t & 3) ^ ((r >> 1) & 3);
        Bgp = Wt + (size_t)(bn + r) * K + c * 8;
    }

    const int swz8 = (quad ^ ((l15 >> 1) & 3)) * 8;
    int aoff[4], boff[4];
    #pragma unroll
    for (int mf = 0; mf < 4; ++mf)
        aoff[mf] = (wrow * 64 + mf * 16 + l15) * 32 + swz8;
    #pragma unroll
    for (int nf = 0; nf < 4; ++nf)
        boff[nf] = 8192 + (wcol * 64 + nf * 16 + l15) * 32 + swz8;

    f32x4 acc[4][4] = {};
    const int NS = K >> 5;   // 32-wide k-steps

#define STAGE(BASE, S) do {                                                 \
        glds16(Agp[0] + (S) * 32, &lds[(BASE) + t * 8]);                    \
        glds16(Agp[1] + (S) * 32, &lds[(BASE) + 4096 + t * 8]);             \
        glds16(Bgp + (S) * 32,    &lds[(BASE) + 8192 + t * 8]);             \
    } while (0)

#define VM3 asm volatile("s_waitcnt vmcnt(3)" ::: "memory")
#define VM0 asm volatile("s_waitcnt vmcnt(0)" ::: "memory")
#define NOVM ((void)0)

#define PHASE(RBASE, STAGEC, VMW) do {                                      \
        bf16x8 af_[4], bf_[4];                                              \
        _Pragma("unroll")                                                   \
        for (int m_ = 0; m_ < 4; ++m_)                                      \
            af_[m_] = *(const bf16x8*)&lds[(RBASE) + aoff[m_]];             \
        _Pragma("unroll")                                                   \
        for (int n_ = 0; n_ < 4; ++n_)                                      \
            bf_[n_] = *(const bf16x8*)&lds[(RBASE) + boff[n_]];             \
        STAGEC;                                                             \
        VMW;                                                                \
        __builtin_amdgcn_s_barrier();                                       \
        asm volatile("s_waitcnt lgkmcnt(0)" ::: "memory");                  \
        __builtin_amdgcn_s_setprio(1);                                      \
        _Pragma("unroll")                                                   \
        for (int m_ = 0; m_ < 4; ++m_)                                      \
            _Pragma("unroll")                                               \
            for (int n_ = 0; n_ < 4; ++n_)                                  \
                acc[m_][n_] = __builtin_amdgcn_mfma_f32_16x16x32_bf16(      \
                    af_[m_], bf_[n_], acc[m_][n_], 0, 0, 0);                \
        __builtin_amdgcn_s_setprio(0);                                      \
        __builtin_amdgcn_s_barrier();                                       \
    } while (0)

    // prologue: stage steps 0,1 (6 loads); vmcnt(3) -> step 0 landed.
    STAGE(0, 0);
    STAGE(12288, 1);
    VM3;
    __builtin_amdgcn_s_barrier();

    int r0 = 0, r1 = 12288, r2 = 24576;
    // main: s = 0 .. NS-3 (stage s+2 into r2 = region (s-1)%3, vmcnt(3))
    for (int s = 0; s < NS - 2; ++s) {
        PHASE(r0, STAGE(r2, s + 2), VM3);
        int tmp = r0; r0 = r1; r1 = r2; r2 = tmp;
    }
    // epilogue: step NS-2 (drain last region), step NS-1 (no wait).
    PHASE(r0, NOVM, VM0);
    PHASE(r1, NOVM, NOVM);

#undef PHASE
#undef STAGE

    if (vt && bn >= 2048) {
        #pragma unroll
        for (int mf = 0; mf < 4; ++mf) {
            #pragma unroll
            for (int nf = 0; nf < 4; ++nf) {
                #pragma unroll
                for (int reg = 0; reg < 4; ++reg) {
                    int row = bm + wrow * 64 + mf * 16 + quad * 4 + reg;
                    int col = bn + wcol * 64 + nf * 16 + l15 - 2048;
                    int bb = row >> 11, tok = row & 2047;
                    int h = col >> 6, d = col & 63;
                    int tg = tok & 63;
                    int sc = (tg & 15) * 4 + (tg >> 4);
                    size_t addr = ((size_t)((bb * 16 + h) * 64 + d) << 11)
                                + (tok & ~63) + sc;
                    vt[addr] = f2bf(acc[mf][nf][reg]);
                }
            }
        }
    } else {
        #pragma unroll
        for (int mf = 0; mf < 4; ++mf) {
            #pragma unroll
            for (int nf = 0; nf < 4; ++nf) {
                #pragma unroll
                for (int reg = 0; reg < 4; ++reg) {
                    int row = bm + wrow * 64 + mf * 16 + quad * 4 + reg;
                    int col = bn + wcol * 64 + nf * 16 + l15;
                    size_t idx = (size_t)row * N + col;
                    float v = acc[mf][nf][reg];
                    if (fuse) v = fmaxf(v, 0.f) + bf2f(resid[idx]);
                    Cbf[idx] = f2bf(v);
                }
            }
        }
    }
}

// ---------------------------------------------------------------------------
// bf16 MFMA GEMM, tile 128x128, BK=64. Used for out-proj: 512 blocks at
// 3-4 blocks/CU — inter-block overlap hides prologue/epilogue (the 8-phase
// variant at 1.0 rounds lost 14 us to exposed tails, round-3 post-mortem).
// ---------------------------------------------------------------------------
__global__ __launch_bounds__(256) void gemm_mfma(const ushort_t* __restrict__ A,
                                                 const ushort_t* __restrict__ Wt,
                                                 ushort_t* __restrict__ Cbf,
                                                 const ushort_t* __restrict__ resid,
                                                 ushort_t* __restrict__ vt,
                                                 int M, int N, int K, int fuse) {
    __shared__ ushort_t As[128 * 64];
    __shared__ ushort_t Bs[128 * 64];
    const int t = threadIdx.x;
    const int w = t >> 6, ln = t & 63;
    const int l15 = ln & 15, quad = ln >> 4;
    const int bm = blockIdx.y * 128, bn = blockIdx.x * 128;
    const int wm = (w & 1) * 64, wn = (w >> 1) * 64;

    const ushort_t* Ap[4];
    const ushort_t* Bp[4];
    #pragma unroll
    for (int j = 0; j < 4; ++j) {
        const int i = t + j * 256;
        const int r = i >> 3;
        const int qg = (i & 7) ^ (r & 7);
        Ap[j] = A  + (size_t)(bm + r) * K + qg * 8;
        Bp[j] = Wt + (size_t)(bn + r) * K + qg * 8;
    }

    f32x4 acc[4][4] = {};

    for (int k0 = 0; k0 < K; k0 += 64) {
        __syncthreads();
        #pragma unroll
        for (int j = 0; j < 4; ++j) {
            glds16(Ap[j] + k0, &As[(t + j * 256) * 8]);
            glds16(Bp[j] + k0, &Bs[(t + j * 256) * 8]);
        }
        __syncthreads();

        #pragma unroll
        for (int kw = 0; kw < 2; ++kw) {
            bf16x8 af[4], bfr[4];
            #pragma unroll
            for (int im = 0; im < 4; ++im) {
                int row = wm + im * 16 + l15;
                int phys = (kw * 4 + quad) ^ (row & 7);
                af[im] = *(const bf16x8*)&As[row * 64 + phys * 8];
            }
            #pragma unroll
            for (int in = 0; in < 4; ++in) {
                int row = wn + in * 16 + l15;
                int phys = (kw * 4 + quad) ^ (row & 7);
                bfr[in] = *(const bf16x8*)&Bs[row * 64 + phys * 8];
            }
            #pragma unroll
            for (int im = 0; im < 4; ++im)
                #pragma unroll
                for (int in = 0; in < 4; ++in)
                    acc[im][in] = __builtin_amdgcn_mfma_f32_16x16x32_bf16(
                        af[im], bfr[in], acc[im][in], 0, 0, 0);
        }
    }

    if (vt && bn >= 2048) {
        #pragma unroll
        for (int im = 0; im < 4; ++im) {
            #pragma unroll
            for (int in = 0; in < 4; ++in) {
                #pragma unroll
                for (int reg = 0; reg < 4; ++reg) {
                    int row = bm + wm + im * 16 + quad * 4 + reg;
                    int col = bn + wn + in * 16 + l15 - 2048;
                    int bb = row >> 11, tok = row & 2047;
                    int h = col >> 6, d = col & 63;
                    int tg = tok & 63;
                    int sc = (tg & 15) * 4 + (tg >> 4);
                    size_t addr = ((size_t)((bb * 16 + h) * 64 + d) << 11)
                                + (tok & ~63) + sc;
                    vt[addr] = f2bf(acc[im][in][reg]);
                }
            }
        }
    } else {
        #pragma unroll
        for (int im = 0; im < 4; ++im) {
            #pragma unroll
            for (int in = 0; in < 4; ++in) {
                #pragma unroll
                for (int reg = 0; reg < 4; ++reg) {
                    int row = bm + wm + im * 16 + quad * 4 + reg;
                    int col = bn + wn + in * 16 + l15;
                    size_t idx = (size_t)row * N + col;
                    float v = acc[im][in][reg];
                    if (fuse) v = fmaxf(v, 0.f) + bf2f(resid[idx]);
                    Cbf[idx] = f2bf(v);
                }
            }
        }
    }
}

// ---------------------------------------------------------------------------
// Flash attention, bf16 MFMA, static-max softmax. Block = 4 waves, 128
// queries (wave w: 32). 128-key K/V tiles, PV in two 64-key phases reusing
// wave-private Ps. Round-8's 64-key stage-ahead pipeline REGRESSED
// (72.3 us, 1.08M LDS bank conflicts from glds write-backs contending
// with ds_reads, VALUBusy 57% from doubled iterations) — keep the
// dedicated-staging-window structure (0 conflicts, <64 us).
// Grid (64 bh, 16): Qt = 15 - blockIdx.y (LPT dispatch).
// T5: s_setprio(1) around the QK^T and PV MFMA clusters.
// ---------------------------------------------------------------------------
__global__ __launch_bounds__(256) void attn_mfma(const ushort_t* __restrict__ qkv,
                                                 const ushort_t* __restrict__ Vt,
                                                 ushort_t* __restrict__ Zb) {
    __shared__ ushort_t Ks[128 * 64];
    __shared__ ushort_t Vs[64 * 128];
    __shared__ ushort_t Ps[4][32 * 72];
    const int t = threadIdx.x, w = t >> 6, ln = t & 63;
    const int l15 = ln & 15, quad = ln >> 4;
    const int bh = blockIdx.x;
    const int b = bh >> 4, h = bh & 15;
    const int Qt = 15 - blockIdx.y;

    bf16x8 ones;
    #pragma unroll
    for (int i = 0; i < 8; ++i) ones[i] = (short)0x3f80;

    int kkey[4], kq[4], vd[4], vcq[4];
    #pragma unroll
    for (int j = 0; j < 4; ++j) {
        int i = t + j * 256;
        kkey[j] = i >> 3;
        kq[j]   = (i & 7) ^ (kkey[j] & 7);
        vd[j]   = i >> 4;
        int cqp = i & 15;
        vcq[j]  = (cqp & 8) | ((cqp & 7) ^ (vd[j] & 7));
    }
    const ushort_t* Kgb = qkv + 1024 + (size_t)b * L_ * QKV_N + h * DH_;
    const ushort_t* Vgb = Vt + (size_t)((b * H_ + h) * DH_) * L_;

    bf16x8 qf[2][2];
    #pragma unroll
    for (int mt = 0; mt < 2; ++mt) {
        const ushort_t* qrow =
            qkv + (size_t)(b * L_ + Qt * 128 + w * 32 + mt * 16 + l15) * QKV_N + h * DH_;
        qf[mt][0] = *(const bf16x8*)(qrow + quad * 8);
        qf[mt][1] = *(const bf16x8*)(qrow + 32 + quad * 8);
    }

    f32x4 acc_o[2][4] = {};
    f32x4 l_acc[2] = {};

    const float c2 = 0.18033688f;   // 0.125 * log2(e)

    for (int kt = 0; kt <= Qt; ++kt) {
        __syncthreads();
        #pragma unroll
        for (int j = 0; j < 4; ++j) {
            glds16(Kgb + (size_t)(kt * 128 + kkey[j]) * QKV_N + kq[j] * 8,
                   &Ks[(t + j * 256) * 8]);
            glds16(Vgb + (size_t)vd[j] * L_ + kt * 128 + vcq[j] * 8,
                   &Vs[(t + j * 256) * 8]);
        }
        __syncthreads();

        const bool masked = (kt == Qt);

        #pragma unroll
        for (int ph = 0; ph < 2; ++ph) {
            if (masked && ph && w < 2) continue;

            f32x4 acc_s[2][4] = {};
            __builtin_amdgcn_s_setprio(1);
            #pragma unroll
            for (int in = 0; in < 4; ++in) {
                const int key = ph * 64 + in * 16 + l15;
                #pragma unroll
                for (int ks = 0; ks < 2; ++ks) {
                    int phys = (ks * 4 + quad) ^ (key & 7);
                    bf16x8 kf = *(const bf16x8*)&Ks[key * 64 + phys * 8];
                    acc_s[0][in] = __builtin_amdgcn_mfma_f32_16x16x32_bf16(
                        qf[0][ks], kf, acc_s[0][in], 0, 0, 0);
                    acc_s[1][in] = __builtin_amdgcn_mfma_f32_16x16x32_bf16(
                        qf[1][ks], kf, acc_s[1][in], 0, 0, 0);
                }
            }
            __builtin_amdgcn_s_setprio(0);

            #pragma unroll
            for (int mt = 0; mt < 2; ++mt) {
                #pragma unroll
                for (int reg = 0; reg < 4; ++reg) {
                    const int row = mt * 16 + quad * 4 + reg;
                    float pv[4];
                    #pragma unroll
                    for (int in = 0; in < 4; ++in) {
                        float s2 = fmaf(acc_s[mt][in][reg], c2, -2.0f);
                        if (masked) {
                            int col = kt * 128 + ph * 64 + in * 16 + l15;
                            int qg  = Qt * 128 + w * 32 + row;
                            s2 = (col > qg) ? -100000.0f : s2;
                        }
                        pv[in] = __builtin_amdgcn_exp2f(s2);
                    }
                    uint_t u01 = __builtin_amdgcn_perm(
                        __float_as_uint(pv[1]), __float_as_uint(pv[0]), 0x07060302u);
                    uint_t u23 = __builtin_amdgcn_perm(
                        __float_as_uint(pv[3]), __float_as_uint(pv[2]), 0x07060302u);
                    uint2* dst = (uint2*)&Ps[w][row * 72 + l15 * 4];
                    *dst = make_uint2(u01, u23);
                }
            }

            __builtin_amdgcn_s_setprio(1);
            #pragma unroll
            for (int ks = 0; ks < 2; ++ks) {
                bf16x8 pf0 = *(const bf16x8*)&Ps[w][(l15) * 72 + ks * 32 + quad * 8];
                bf16x8 pf1 = *(const bf16x8*)&Ps[w][(16 + l15) * 72 + ks * 32 + quad * 8];
                #pragma unroll
                for (int in = 0; in < 4; ++in) {
                    const int d = in * 16 + l15;
                    int physv = ph * 8 + (((ks * 4 + quad) ^ (d & 7)));
                    bf16x8 vf = *(const bf16x8*)&Vs[d * 128 + physv * 8];
                    acc_o[0][in] = __builtin_amdgcn_mfma_f32_16x16x32_bf16(
                        vf, pf0, acc_o[0][in], 0, 0, 0);
                    acc_o[1][in] = __builtin_amdgcn_mfma_f32_16x16x32_bf16(
                        vf, pf1, acc_o[1][in], 0, 0, 0);
                }
                l_acc[0] = __builtin_amdgcn_mfma_f32_16x16x32_bf16(ones, pf0, l_acc[0], 0, 0, 0);
                l_acc[1] = __builtin_amdgcn_mfma_f32_16x16x32_bf16(ones, pf1, l_acc[1], 0, 0, 0);
            }
            __builtin_amdgcn_s_setprio(0);
        }
    }

    #pragma unroll
    for (int mt = 0; mt < 2; ++mt) {
        const float inv = 1.0f / l_acc[mt][0];
        const int row = b * L_ + Qt * 128 + w * 32 + mt * 16 + l15;
        #pragma unroll
        for (int in = 0; in < 4; ++in) {
            const int dbase = h * DH_ + in * 16 + quad * 4;
            f32x4 a = acc_o[mt][in];
            ushort4 o;
            o.x = f2bf(a[0] * inv); o.y = f2bf(a[1] * inv);
            o.z = f2bf(a[2] * inv); o.w = f2bf(a[3] * inv);
            *(ushort4*)(Zb + (size_t)row * D_ + dbase) = o;
        }
    }
}

// ---------------------------------------------------------------------------
// LayerNorm over last dim (1024), bf16 input, fp32 out. 256-thread blocks,
// 4 rows per block (one row per wave; shuffles are wave-local).
// ---------------------------------------------------------------------------
__global__ __launch_bounds__(256) void ln_kernel(const ushort_t* __restrict__ Y,
                                                 const float* __restrict__ gamma,
                                                 const float* __restrict__ beta,
                                                 float* __restrict__ out) {
    const int row = blockIdx.x * 4 + (threadIdx.x >> 6);
    const int t = threadIdx.x & 63;
    const ushort_t* y = Y + (size_t)row * D_;

    float v[16];
    #pragma unroll
    for (int s = 0; s < 4; ++s) {
        ushort4 u = *(const ushort4*)(y + s * 256 + t * 4);
        v[s * 4 + 0] = bf2f(u.x);
        v[s * 4 + 1] = bf2f(u.y);
        v[s * 4 + 2] = bf2f(u.z);
        v[s * 4 + 3] = bf2f(u.w);
    }

    float sum = 0.f;
    #pragma unroll
    for (int i = 0; i < 16; ++i) sum += v[i];
    #pragma unroll
    for (int k = 1; k < 64; k <<= 1) sum += __shfl_xor(sum, k, 64);
    const float mu = sum * (1.f / (float)D_);

    float var = 0.f;
    #pragma unroll
    for (int i = 0; i < 16; ++i) {
        float d = v[i] - mu;
        var += d * d;
    }
    #pragma unroll
    for (int k = 1; k < 64; k <<= 1) var += __shfl_xor(var, k, 64);
    const float rstd = rsqrtf(var * (1.f / (float)D_) + 1e-12f);

    #pragma unroll
    for (int s = 0; s < 4; ++s) {
        const int col = s * 256 + t * 4;
        float4 g  = *(const float4*)(gamma + col);
        float4 bb = *(const float4*)(beta + col);
        float4 o;
        o.x = (v[s * 4 + 0] - mu) * rstd * g.x + bb.x;
        o.y = (v[s * 4 + 1] - mu) * rstd * g.y + bb.y;
        o.z = (v[s * 4 + 2] - mu) * rstd * g.z + bb.z;
        o.w = (v[s * 4 + 3] - mu) * rstd * g.w + bb.w;
        *(float4*)(out + (size_t)row * D_ + col) = o;
    }
}

// ---------------------------------------------------------------------------
extern "C" void kernel_launch(void* const* d_in, const int* in_sizes, int n_in,
                              void* d_out, int out_size, void* d_ws, size_t ws_size,
                              hipStream_t stream) {
    const float* x     = (const float*)d_in[0];
    const float* Wq    = (const float*)d_in[1];
    const float* Wk    = (const float*)d_in[2];
    const float* Wv    = (const float*)d_in[3];
    const float* Wo    = (const float*)d_in[4];
    const float* gamma = (const float*)d_in[5];
    const float* beta  = (const float*)d_in[6];
    float* out = (float*)d_out;

    char* ws = (char*)d_ws;
    ushort_t* x_bf = (ushort_t*)(ws);                 // 16 MB
    ushort_t* wcat = (ushort_t*)(ws + (16u  << 20));  //  6 MB (Wq^T|Wk^T|Wv^T)
    ushort_t* wto  = (ushort_t*)(ws + (22u  << 20));  //  2 MB
    ushort_t* qkv  = (ushort_t*)(ws + (24u  << 20));  // 48 MB [8192][3072] (V region unused)
    ushort_t* vt   = (ushort_t*)(ws + (72u  << 20));  // 16 MB
    ushort_t* z_bf = (ushort_t*)(ws + (88u  << 20));  // 16 MB
    ushort_t* y_bf = (ushort_t*)(ws + (104u << 20));  // 16 MB

    const int M = B_ * L_;

    prep<<<dim3(16, 16, 5), 256, 0, stream>>>(Wq, Wk, Wv, Wo, x, wcat, wto, x_bf);

    // QKV: 256x128-tile, 3-region ring, 72 KiB LDS -> 2 blocks/CU (round-10)
    gemm8p<<<dim3(QKV_N / 128, M / 256), 512, 0, stream>>>(
        x_bf, wcat, qkv, nullptr, vt, M, QKV_N, D_, 0);

    // attn: 128-key tiles, dedicated staging window (round-7 best)
    attn_mfma<<<dim3(B_ * H_, 16), 256, 0, stream>>>(qkv, vt, z_bf);

    // out-proj: 128^2, 512 blocks at 3-4/CU (inter-block overlap regime)
    gemm_mfma<<<dim3(D_ / 128, M / 128), 256, 0, stream>>>(
        z_bf, wto, y_bf, x_bf, nullptr, M, D_, D_, 1);

    ln_kernel<<<M / 4, 256, 0, stream>>>(y_bf, gamma, beta, out);
}